// Round 11
// baseline (2144.399 us; speedup 1.0000x reference)
//
#include <hip/hip_runtime.h>
#include <stdint.h>

// B=256,T=512,H=256,4 layers. 8 groups x MB=32, 4 layers x 8 slices, weights in
// VGPRs (r6/r9/r10-proven). Round 11: TAGGED sibling exchange — h ring words are
// u64 (tag<<32 | 2xbf16); consumers poll data directly (no drain/flag/detect on
// the critical path). Up/down flags are slack-bearing, register-cached, published
// post-h-poll (vmcnt0-certified). Raw s_barrier + manual waitcnt throughout.
#define T_ 512
#define H_ 256
#define MB 32
#define NBUF 8
#define SLOTW 4096     // u64 words per h image slot (32 KB)
#define NWG 256

typedef __attribute__((ext_vector_type(8))) short  short8;
typedef __attribute__((ext_vector_type(4))) float  floatx4;
typedef __attribute__((ext_vector_type(4))) unsigned int uint4v;
typedef unsigned long long ull;

struct Params {
  const float* x;
  const float* Wih[4]; const float* Whh[4]; const float* bih[4]; const float* bhh[4];
  const float* fcW; const float* fcb;
  int* flags;    // [32 cells][32 ints], one 128B line per (g,l); [slice] = ticks certified
  ull* hring;    // [32 cells][NBUF][SLOTW] tagged h images (A-fragment word order)
};

__device__ __forceinline__ short f2bf(float f){
  uint32_t u = __builtin_bit_cast(uint32_t, f);
  u += 0x7fffu + ((u >> 16) & 1u);          // RNE
  return (short)(u >> 16);
}
__device__ __forceinline__ float bf2f(short s){
  uint32_t u = ((uint32_t)(uint16_t)s) << 16;
  return __builtin_bit_cast(float, u);
}
__device__ __forceinline__ float sigm(float v){ return 1.0f / (1.0f + __expf(-v)); }
__device__ __forceinline__ float tanh_(float v){
  float a = fabsf(v);
  float e = __expf(-2.0f * a);
  float r = (1.0f - e) / (1.0f + e);
  return v < 0.0f ? -r : r;
}

__device__ __forceinline__ void a_st64(ull* p, ull v){
  __hip_atomic_store(p, v, __ATOMIC_RELAXED, __HIP_MEMORY_SCOPE_AGENT);
}
__device__ __forceinline__ int a_ldi(const int* p){
  return __hip_atomic_load(p, __ATOMIC_RELAXED, __HIP_MEMORY_SCOPE_AGENT);
}
__device__ __forceinline__ void a_sti(int* p, int v){
  __hip_atomic_store(p, v, __ATOMIC_RELAXED, __HIP_MEMORY_SCOPE_AGENT);
}
__device__ __forceinline__ void ld16(uint4v& d, const void* p){
  asm volatile("global_load_dwordx4 %0, %1, off sc0 sc1" : "=v"(d) : "v"(p));
}
__device__ __forceinline__ void ldf32(float& d, const void* p){
  asm volatile("global_load_dword %0, %1, off" : "=v"(d) : "v"(p));
}
__device__ __forceinline__ void waitvm0(){ asm volatile("s_waitcnt vmcnt(0)" ::: "memory"); }
__device__ __forceinline__ void waitvm2(){ asm volatile("s_waitcnt vmcnt(2)" ::: "memory"); }
__device__ __forceinline__ void bar_lds(){
  asm volatile("s_waitcnt lgkmcnt(0)" ::: "memory");
  __builtin_amdgcn_s_barrier();
}

#define MFMA(a,b,c) __builtin_amdgcn_mfma_f32_16x16x32_bf16((a),(b),(c),0,0,0)

// flag poll with per-lane register cache (flags are monotone)
__device__ __forceinline__ void wpoll_upd(const int* p, int thr, bool& dead, int& cache){
  if (dead) return;
  int guard = 0;
  for (;;){
    int v = a_ldi(p);
    cache = v;
    if (__all((int)(v >= thr))) break;
    if (++guard > (1 << 16)) { dead = true; break; }
  }
}

template<bool L0>
__device__ __forceinline__ void run_cell(const Params& p, int g, int l, int slice,
    short* a_frag, float (*g_lds)[MB][33], float (*bias_lds)[32],
    float (*wih0_lds)[32], float* x0_lds)
{
  constexpr int KBT = L0 ? 8 : 16;
  const int tid = threadIdx.x, lane = tid & 63, wave = tid >> 6;  // wave = gate
  const int n15 = lane & 15, q4 = lane >> 4;

  int* fl_self = p.flags + (g * 4 + l) * 32;
  int* fl_up   = L0 ? fl_self : fl_self - 32;
  int* fl_down = (l < 3) ? fl_self + 32 : fl_self;
  ull* hr_self = p.hring + (size_t)((g * 4 + l) * NBUF) * SLOTW;
  const ull* hr_up = L0 ? (const ull*)nullptr : hr_self - (size_t)NBUF * SLOTW;

  if (tid < 128){
    int gt = tid >> 5, j = tid & 31;
    int gr = gt * 256 + slice * 32 + j;
    bias_lds[gt][j] = p.bih[l][gr] + p.bhh[l][gr];
    if (L0) wih0_lds[gt][j] = p.Wih[0][gr];    // W_ih0 is [1024 x 1]
  }

  // ---- Weight B-fragments resident in VGPRs (proven mapping) ----
  short8 wf0[KBT], wf1[KBT];
  const int g0 = wave * 256 + slice * 32 + n15;
  const int g1 = g0 + 16;
  #pragma unroll
  for (int kb = 0; kb < KBT; ++kb){
    const float* base; int kk;
    if (L0)          { base = p.Whh[0]; kk = kb * 32 + q4 * 8; }
    else if (kb < 8) { base = p.Wih[l]; kk = kb * 32 + q4 * 8; }
    else             { base = p.Whh[l]; kk = (kb - 8) * 32 + q4 * 8; }
    const float* p0 = base + (size_t)g0 * H_ + kk;
    const float* p1 = base + (size_t)g1 * H_ + kk;
    short8 a, b;
    #pragma unroll
    for (int i = 0; i < 8; ++i){ a[i] = f2bf(p0[i]); b[i] = f2bf(p1[i]); }
    wf0[kb] = a; wf1[kb] = b;
  }

  float c00 = 0.f, c01 = 0.f, c10 = 0.f, c11 = 0.f;
  const int r0 = (tid >> 4) * 2, r1 = r0 + 1;
  const int pc = (tid & 15) * 2;

  // slack-bearing flag gates: lanes 8-15 upstream (x-gate >= t+2), 16-23 down (>= t-6)
  const int* pp; int dlt;
  if (lane >= 8 && lane < 16 && !L0){ pp = fl_up + (lane - 8); dlt = 2; }
  else if (lane >= 16 && lane < 24 && l < 3){ pp = fl_down + (lane - 16); dlt = -6; }
  else { pp = fl_self + (lane & 7); dlt = -1000000; }
  int fcache = 0;
  bool dead = false;

  uint4v* fragv = (uint4v*)a_frag;
  constexpr int hbase = L0 ? 0 : 1024;    // u128 index of h rows in LDS
  uint4v px[8];
  float xcur = 0.f;

  // ---- Prologue: x(0) = tagged-poll upstream slot 0 for tag 1 ----
  if (!L0){
    int guard = 0;
    const char* s0 = (const char*)hr_up;
    for (;;){
      #pragma unroll
      for (int k = 0; k < 4; ++k){
        ld16(px[2*k],   s0 + (size_t)(k * 256 + tid) * 32);
        ld16(px[2*k+1], s0 + (size_t)(k * 256 + tid) * 32 + 16);
      }
      waitvm0();
      bool ok = true;
      #pragma unroll
      for (int j = 0; j < 8; ++j) ok = ok && (px[j].y == 1u) && (px[j].w == 1u);
      if (__all((int)ok)) break;
      if (++guard > (1 << 14)) { dead = true; break; }
    }
  } else if (wave == 0 && lane < MB){
    ldf32(xcur, &p.x[(size_t)(g * MB + lane) * T_]);
    waitvm0();
  }
  __syncthreads();

  for (int t = 0; t < T_; ++t){
    // phase 0: land px/xcur (2 newest outstanding = our own tagged stores)
    if (t > 0) waitvm2();

    // phase 1: stage x (strip tags; lane-contiguous, conflict-free)
    if (!L0){
      #pragma unroll
      for (int k = 0; k < 4; ++k){
        uint4v d;
        d.x = px[2*k].x;   d.y = px[2*k].z;
        d.z = px[2*k+1].x; d.w = px[2*k+1].z;
        fragv[k * 256 + tid] = d;
      }
    } else if (wave == 0 && lane < MB){
      x0_lds[lane] = xcur;
    }

    // phase 2: issue tagged h(t-1) loads
    uint4v hv[8];
    const char* hs = (const char*)(hr_self + (size_t)((t - 1) & 7) * SLOTW);
    if (t > 0){
      #pragma unroll
      for (int k = 0; k < 4; ++k){
        ld16(hv[2*k],   hs + (size_t)(k * 256 + tid) * 32);
        ld16(hv[2*k+1], hs + (size_t)(k * 256 + tid) * 32 + 16);
      }
    }

    // phase 3: slack flag gates via register cache (poll rarely)
    { int thr = t + dlt; if (thr > T_) thr = 0;
      if (!__all((int)(fcache >= thr))) wpoll_upd(pp, thr, dead, fcache); }

    // phase 4: optimistic x(t+1) prefetch (gate certified by up-flag >= t+2)
    const bool pf = (t + 1 < T_);
    if (!L0){
      if (pf){
        const char* us = (const char*)(hr_up + (size_t)((t + 1) & 7) * SLOTW);
        #pragma unroll
        for (int k = 0; k < 4; ++k){
          ld16(px[2*k],   us + (size_t)(k * 256 + tid) * 32);
          ld16(px[2*k+1], us + (size_t)(k * 256 + tid) * 32 + 16);
        }
      }
    } else if (wave == 0 && lane < MB && pf){
      ldf32(xcur, &p.x[(size_t)(g * MB + lane) * T_ + (t + 1)]);
    }
    bar_lds();   // bar1: x rows / x0 visible; h + px loads in flight

    floatx4 acc[2][2][2] = {};
    if (!L0){
      #pragma unroll
      for (int kb = 0; kb < 8; ++kb){        // x-MFMA hides part of h RT
        #pragma unroll
        for (int mt = 0; mt < 2; ++mt){
          short8 af = *(short8*)&a_frag[(kb * 2 + mt) * 512 + lane * 8];
          int pr = kb & 1;
          acc[mt][0][pr] = MFMA(af, wf0[kb], acc[mt][0][pr]);
          acc[mt][1][pr] = MFMA(af, wf1[kb], acc[mt][1][pr]);
        }
      }
    }

    // phase 6: h tag-poll (data IS the flag) + stage
    if (t > 0){
      int guard = 0;
      for (;;){
        waitvm0();
        bool ok = true;
        #pragma unroll
        for (int j = 0; j < 8; ++j)
          ok = ok && (hv[j].y == (unsigned)t) && (hv[j].w == (unsigned)t);
        if (__all((int)ok)) break;
        if (++guard > (1 << 14)) { dead = true; break; }
        #pragma unroll
        for (int k = 0; k < 4; ++k){
          ld16(hv[2*k],   hs + (size_t)(k * 256 + tid) * 32);
          ld16(hv[2*k+1], hs + (size_t)(k * 256 + tid) * 32 + 16);
        }
      }
      #pragma unroll
      for (int k = 0; k < 4; ++k){
        uint4v d;
        d.x = hv[2*k].x;   d.y = hv[2*k].z;
        d.z = hv[2*k+1].x; d.w = hv[2*k+1].z;
        fragv[hbase + k * 256 + tid] = d;
      }
    } else {
      uint4v z = {0, 0, 0, 0};
      #pragma unroll
      for (int k = 0; k < 4; ++k) fragv[hbase + k * 256 + tid] = z;
    }
    bar_lds();   // bar2: h rows visible; all waves past their vmcnt0

    // publish flag t: certifies h(t-1) fully at L3 (each wave's vmcnt0 above)
    if (tid == 0 && t > 0) a_sti(fl_self + slice, t);

    // h-part MFMA
    #pragma unroll
    for (int kb = (L0 ? 0 : 8); kb < KBT; ++kb){
      #pragma unroll
      for (int mt = 0; mt < 2; ++mt){
        short8 af = *(short8*)&a_frag[(kb * 2 + mt) * 512 + lane * 8];
        int pr = kb & 1;
        acc[mt][0][pr] = MFMA(af, wf0[kb], acc[mt][0][pr]);
        acc[mt][1][pr] = MFMA(af, wf1[kb], acc[mt][1][pr]);
      }
    }
    #pragma unroll
    for (int mt = 0; mt < 2; ++mt){
      floatx4 s0 = acc[mt][0][0] + acc[mt][0][1];
      floatx4 s1 = acc[mt][1][0] + acc[mt][1][1];
      int mrow = mt * 16 + q4 * 4;
      #pragma unroll
      for (int r = 0; r < 4; ++r){
        g_lds[wave][mrow + r][n15]      = s0[r];
        g_lds[wave][mrow + r][16 + n15] = s1[r];
      }
    }
    bar_lds();   // bar3: gates visible

    // pointwise -> tagged u64 stores (tick ends at store issue; no drain/flag)
    {
      float xs0 = 0.f, xs1 = 0.f;
      if (L0){ xs0 = x0_lds[r0]; xs1 = x0_lds[r1]; }
      ull* slot = hr_self + (size_t)(t & 7) * SLOTW;
      const ull tagv = ((ull)(unsigned)(t + 1)) << 32;
      #pragma unroll
      for (int rr = 0; rr < 2; ++rr){
        const int row = rr ? r1 : r0;
        const float xs = rr ? xs1 : xs0;
        float gi0 = g_lds[0][row][pc]   + bias_lds[0][pc];
        float gi1 = g_lds[0][row][pc+1] + bias_lds[0][pc+1];
        float gf0 = g_lds[1][row][pc]   + bias_lds[1][pc];
        float gf1 = g_lds[1][row][pc+1] + bias_lds[1][pc+1];
        float gg0 = g_lds[2][row][pc]   + bias_lds[2][pc];
        float gg1 = g_lds[2][row][pc+1] + bias_lds[2][pc+1];
        float go0 = g_lds[3][row][pc]   + bias_lds[3][pc];
        float go1 = g_lds[3][row][pc+1] + bias_lds[3][pc+1];
        if (L0){
          gi0 += xs * wih0_lds[0][pc]; gi1 += xs * wih0_lds[0][pc+1];
          gf0 += xs * wih0_lds[1][pc]; gf1 += xs * wih0_lds[1][pc+1];
          gg0 += xs * wih0_lds[2][pc]; gg1 += xs * wih0_lds[2][pc+1];
          go0 += xs * wih0_lds[3][pc]; go1 += xs * wih0_lds[3][pc+1];
        }
        float i0 = sigm(gi0), i1 = sigm(gi1);
        float f0 = sigm(gf0), f1 = sigm(gf1);
        float gv0 = tanh_(gg0), gv1 = tanh_(gg1);
        float o0 = sigm(go0), o1 = sigm(go1);
        float& ca = rr ? c10 : c00;
        float& cb = rr ? c11 : c01;
        ca = f0 * ca + i0 * gv0;
        cb = f1 * cb + i1 * gv1;
        float h0 = o0 * tanh_(ca);
        float h1 = o1 * tanh_(cb);
        unsigned pk = (unsigned)(uint16_t)f2bf(h0) | ((unsigned)(uint16_t)f2bf(h1) << 16);
        unsigned off = (unsigned)((slice * 2 + (row >> 4)) * 512
                     + ((pc >> 3) * 16 + (row & 15)) * 8 + (pc & 7));
        a_st64(slot + (off >> 1), tagv | (ull)pk);
      }
    }
  } // t

  // epilogue: certify final stores, publish T_
  waitvm0();
  __syncthreads();
  if (tid == 0) a_sti(fl_self + slice, T_);
}

__global__ __launch_bounds__(256, 1) void lstm_kernel(Params p){
  __shared__ short a_frag[32 * 512];          // 32 KB (x rows 0..15, h rows 16..31)
  __shared__ float g_lds[4][MB][33];
  __shared__ float bias_lds[4][32];
  __shared__ float wih0_lds[4][32];
  __shared__ float x0_lds[MB];

  const int wg    = blockIdx.x;
  const int g     = wg >> 5;
  const int l     = (wg >> 3) & 3;
  const int slice = wg & 7;
  if (l == 0) run_cell<true >(p, g, 0, slice, a_frag, g_lds, bias_lds, wih0_lds, x0_lds);
  else        run_cell<false>(p, g, l, slice, a_frag, g_lds, bias_lds, wih0_lds, x0_lds);
}

// FC on h_3(T-1): decode TAGGED fragment image, cell (g,3), ring slot 7
__global__ void fc_kernel(const ull* __restrict__ hring, const float* __restrict__ fcW,
                          const float* __restrict__ fcb, float* __restrict__ out){
  int b = blockIdx.x, lane = threadIdx.x;
  int g = b >> 5, m = b & 31;
  int mt = m >> 4, mm = m & 15;
  const short* base = (const short*)(hring
      + (size_t)((g * 4 + 3) * NBUF + ((T_ - 1) & 7)) * SLOTW);
  float s = 0.f;
  #pragma unroll
  for (int k = 0; k < 4; ++k){
    int d = lane + 64 * k;
    int kb = d >> 5, koff = d & 31;
    int sidx = (kb * 2 + mt) * 512 + ((koff >> 3) * 16 + mm) * 8 + (koff & 7);
    short hv = base[(sidx >> 1) * 4 + (sidx & 1)];   // u64 = [d0,d1,tag,tag] shorts
    s += bf2f(hv) * fcW[d];
  }
  #pragma unroll
  for (int off = 32; off; off >>= 1) s += __shfl_down(s, off);
  if (lane == 0) out[b] = s + fcb[0];
}

extern "C" void kernel_launch(void* const* d_in, const int* in_sizes, int n_in,
                              void* d_out, int out_size, void* d_ws, size_t ws_size,
                              hipStream_t stream) {
  Params P;
  P.x = (const float*)d_in[0];
  for (int l = 0; l < 4; ++l){
    P.Wih[l] = (const float*)d_in[1 + 4*l];
    P.Whh[l] = (const float*)d_in[2 + 4*l];
    P.bih[l] = (const float*)d_in[3 + 4*l];
    P.bhh[l] = (const float*)d_in[4 + 4*l];
  }
  P.fcW = (const float*)d_in[17];
  P.fcb = (const float*)d_in[18];

  char* ws = (char*)d_ws;
  P.flags = (int*)ws;                        // 32 lines x 128 B = 4 KB
  P.hring = (ull*)(ws + 16384);              // 32 x 8 x 32 KB = 8 MB

  hipMemsetAsync(ws, 0, 8192, stream);
  hipLaunchKernelGGL(lstm_kernel, dim3(NWG), dim3(256), 0, stream, P);
  hipLaunchKernelGGL(fc_kernel, dim3(256), dim3(64), 0, stream,
                     P.hring, P.fcW, P.fcb, (float*)d_out);
}